// Round 1
// baseline (161.190 us; speedup 1.0000x reference)
//
#include <hip/hip_runtime.h>
#include <hip/hip_bf16.h>

#define B_ 8
#define L_ 2048
#define D_ 128
#define BL_ (B_ * L_)
#define DELTA2 0.016f   // 2*delta; delta=0.008 >= rigorous bf16 dot bound (0.004) with 2x margin
#define QCAP 4096
#define ROWS 32

typedef __attribute__((ext_vector_type(8))) short bf16x8;
typedef __attribute__((ext_vector_type(4))) float f32x4;

// ---------------- K1: normalize + bf16 cast ----------------
__global__ void k_norm(const float* __restrict__ ctx,
                       float* __restrict__ cn, float* __restrict__ en,
                       ushort* __restrict__ cnb, ushort* __restrict__ enb) {
    int wid  = blockIdx.x * 4 + (threadIdx.x >> 6);   // 0..32767
    int lane = threadIdx.x & 63;
    int b   = wid >> 12;
    int rem = wid & 4095;
    int c   = rem >> 11;
    int l   = rem & 2047;

    const float* src = ctx + (size_t)wid * D_;
    float2 v = ((const float2*)src)[lane];
    float ss = v.x * v.x + v.y * v.y;
    #pragma unroll
    for (int off = 32; off; off >>= 1) ss += __shfl_down(ss, off, 64);
    ss = __shfl(ss, 0, 64);
    float n = fmaxf(sqrtf(ss), 1e-8f);
    float ox = v.x / n, oy = v.y / n;

    size_t ro = (size_t)(b * L_ + l) * D_;
    float* dst = (c == 0 ? cn : en) + ro;
    ((float2*)dst)[lane] = make_float2(ox, oy);

    __hip_bfloat16 hx = __float2bfloat16(ox), hy = __float2bfloat16(oy);
    ushort ux = *(ushort*)&hx, uy = *(ushort*)&hy;
    ushort* dstb = (c == 0 ? cnb : enb) + ro;
    ((ushort2*)dstb)[lane] = make_ushort2(ux, uy);
}

// ---------------- K2: fused sim + argmax with ONLINE candidate capture ----------------
// grid 512: b = blk&7 (XCD-local), rb = blk>>3 (0..63). Block = 32 rows x 2048 cols,
// 8 waves, wave w owns cols [w*256, w*256+256) as 4 tiles of 32x64.
// Single MFMA pass: per tile, reduce per-row tile max across lanes, update running
// row max, and enqueue (val,row,col) for any acc >= runmax - 2delta. Running max
// only grows => capture set is a superset of {val >= final rowmax - 2delta}; the
// final-threshold filter in phase 3 restores exactly the old candidate set.
__global__ __launch_bounds__(512, 4) void k_sim(const ushort* __restrict__ cnb,
                                                const ushort* __restrict__ enb,
                                                const float* __restrict__ cn,
                                                const float* __restrict__ en,
                                                int* __restrict__ finalidx) {
    __shared__ float wrowmax[8][ROWS];
    __shared__ float rowth_l[ROWS];
    __shared__ unsigned long long bestw[8][ROWS];
    __shared__ unsigned long long qbuf[QCAP];   // (f32 bits << 32) | row<<11 | col
    __shared__ int qn;

    int bid = blockIdx.x;
    int b = bid & 7, rb = bid >> 3;
    int row0 = rb * ROWS;
    int tid = threadIdx.x;
    int wave = tid >> 6, lane = tid & 63;
    int m = lane & 15, q = lane >> 4;

    if (tid == 0) qn = 0;
    if (lane < ROWS) bestw[wave][lane] = 0ULL;
    __syncthreads();

    const ushort* Ab  = cnb + ((size_t)(b * L_) + row0) * D_;
    const ushort* Bb0 = enb + (size_t)(b * L_) * D_;

    // A fragments: 32 rows x 128 k, 32 VGPRs, live for the whole kernel
    bf16x8 Areg[8];
    #pragma unroll
    for (int rt = 0; rt < 2; ++rt)
        #pragma unroll
        for (int kc = 0; kc < 4; ++kc)
            Areg[rt * 4 + kc] = *(const bf16x8*)(Ab + (size_t)(rt * 16 + m) * D_ + kc * 32 + q * 8);

    float runmax[8];
    #pragma unroll
    for (int s = 0; s < 8; ++s) runmax[s] = -3.0e38f;

    for (int t = 0; t < 4; ++t) {
        int col0 = wave * 256 + t * 64;
        const ushort* Bb = Bb0 + (size_t)col0 * D_;

        f32x4 acc[2][4];
        #pragma unroll
        for (int rt = 0; rt < 2; ++rt)
            #pragma unroll
            for (int ct = 0; ct < 4; ++ct) acc[rt][ct] = (f32x4){0.f, 0.f, 0.f, 0.f};
        #pragma unroll
        for (int kc = 0; kc < 4; ++kc) {
            bf16x8 bfrag[4];
            #pragma unroll
            for (int ct = 0; ct < 4; ++ct)
                bfrag[ct] = *(const bf16x8*)(Bb + (size_t)(ct * 16 + m) * D_ + kc * 32 + q * 8);
            #pragma unroll
            for (int rt = 0; rt < 2; ++rt)
                #pragma unroll
                for (int ct = 0; ct < 4; ++ct)
                    acc[rt][ct] = __builtin_amdgcn_mfma_f32_16x16x32_bf16(
                        Areg[rt * 4 + kc], bfrag[ct], acc[rt][ct], 0, 0, 0);
        }

        // ---- online capture: tile row-max (cross-lane), threshold, enqueue ----
        #pragma unroll
        for (int rt = 0; rt < 2; ++rt)
            #pragma unroll
            for (int reg = 0; reg < 4; ++reg) {
                int s = rt * 4 + reg;
                float mx4 = fmaxf(fmaxf(acc[rt][0][reg], acc[rt][1][reg]),
                                  fmaxf(acc[rt][2][reg], acc[rt][3][reg]));
                float trm = mx4;
                trm = fmaxf(trm, __shfl_xor(trm, 1, 64));
                trm = fmaxf(trm, __shfl_xor(trm, 2, 64));
                trm = fmaxf(trm, __shfl_xor(trm, 4, 64));
                trm = fmaxf(trm, __shfl_xor(trm, 8, 64));
                runmax[s] = fmaxf(runmax[s], trm);
                float th = runmax[s] - DELTA2;
                if (mx4 >= th) {
                    int row = rt * 16 + q * 4 + reg;
                    #pragma unroll
                    for (int ct = 0; ct < 4; ++ct)
                        if (acc[rt][ct][reg] >= th) {
                            int pos = atomicAdd(&qn, 1);
                            if (pos < QCAP)
                                qbuf[pos] =
                                    ((unsigned long long)__float_as_uint(acc[rt][ct][reg]) << 32) |
                                    (unsigned)(row << 11) | (unsigned)(col0 + ct * 16 + m);
                        }
                }
            }
    }

    // ---- cross-wave row threshold ----
    if (m == 0) {
        #pragma unroll
        for (int rt = 0; rt < 2; ++rt)
            #pragma unroll
            for (int reg = 0; reg < 4; ++reg)
                wrowmax[wave][rt * 16 + q * 4 + reg] = runmax[rt * 4 + reg];
    }
    __syncthreads();
    if (tid < ROWS) {
        float rm = wrowmax[0][tid];
        #pragma unroll
        for (int w = 1; w < 8; ++w) rm = fmaxf(rm, wrowmax[w][tid]);
        rowth_l[tid] = rm - DELTA2;
    }
    __syncthreads();

    // ---- phase 3: filter by final threshold, wave-parallel exact (double) dots ----
    int qtot = min(qn, QCAP);
    for (int e = wave; e < qtot; e += 8) {
        unsigned long long pk = qbuf[e];
        int rl  = (int)((pk >> 11) & 31u);
        int col = (int)(pk & 2047u);
        float v = __uint_as_float((unsigned)(pk >> 32));
        if (v < rowth_l[rl]) continue;   // wave-uniform branch
        const float* ar = cn + ((size_t)(b * L_) + row0 + rl) * D_;
        const float* br = en + ((size_t)(b * L_) + col) * D_;
        float2 x = ((const float2*)ar)[lane];
        float2 y = ((const float2*)br)[lane];
        double sdot = (double)x.x * y.x + (double)x.y * y.y;
        #pragma unroll
        for (int off = 32; off; off >>= 1) sdot += __shfl_down(sdot, off, 64);
        if (lane == 0) {
            unsigned long long ub = (unsigned long long)__double_as_longlong(sdot);
            ub = (ub & 0x8000000000000000ULL) ? ~ub : (ub | 0x8000000000000000ULL);
            ub = (ub & ~0x7FFULL) | (unsigned long long)(2047 - col);  // tie -> lowest col
            if (ub > bestw[wave][rl]) bestw[wave][rl] = ub;            // wave-private, race-free
        }
    }
    __syncthreads();
    if (tid < ROWS) {
        unsigned long long bb = bestw[0][tid];
        #pragma unroll
        for (int w = 1; w < 8; ++w) { unsigned long long t2 = bestw[w][tid]; if (t2 > bb) bb = t2; }
        finalidx[b * L_ + row0 + tid] = 2047 - (int)(bb & 0x7FFULL);
    }
}

// ---------------- K3: g[r] = relu(X[r]@W1+b1)@W2 + b2, fp32, BM=64 4x8, grid 512 ----------------
__global__ __launch_bounds__(256) void k_feval(
        const float* __restrict__ X,
        const float* __restrict__ W1, const float* __restrict__ b1,
        const float* __restrict__ W2, const float* __restrict__ b2,
        float* __restrict__ g) {
    __shared__ __align__(16) float As[32][68];
    __shared__ __align__(16) float Bs[32][132];
    __shared__ float redv[64][16];

    int tid = threadIdx.x;
    int tx = tid & 15, ty = tid >> 4;
    int r  = tid >> 3, kg = tid & 7;
    int row0 = blockIdx.x * 64;
    const float* Ab = X + (size_t)row0 * D_;

    float acc[4][8];
    #pragma unroll
    for (int i = 0; i < 4; ++i)
        #pragma unroll
        for (int j = 0; j < 8; ++j) acc[i][j] = 0.0f;

    for (int kc = 0; kc < 4; ++kc) {
        __syncthreads();
        #pragma unroll
        for (int p = 0; p < 2; ++p) {
            int rr = r + 32 * p;
            float4 v = *(const float4*)(Ab + (size_t)rr * D_ + kc * 32 + kg * 4);
            As[kg][rr]      = v.x;
            As[8 + kg][rr]  = v.y;
            As[16 + kg][rr] = v.z;
            As[24 + kg][rr] = v.w;
        }
        {
            int kr = r, phys = (kr & 3) * 8 + (kr >> 2);
            const float* srcp = W1 + (size_t)(kc * 32 + kr) * D_ + kg * 16;
            #pragma unroll
            for (int qq = 0; qq < 4; ++qq)
                *(float4*)&Bs[phys][kg * 16 + qq * 4] = *(const float4*)(srcp + qq * 4);
        }
        __syncthreads();
        #pragma unroll
        for (int k = 0; k < 32; ++k) {
            float a[4], bb[8];
            *(float4*)&a[0]  = *(const float4*)&As[k][ty * 4];
            *(float4*)&bb[0] = *(const float4*)&Bs[k][tx * 4];
            *(float4*)&bb[4] = *(const float4*)&Bs[k][64 + tx * 4];
            #pragma unroll
            for (int i = 0; i < 4; ++i)
                #pragma unroll
                for (int j = 0; j < 8; ++j)
                    acc[i][j] = fmaf(a[i], bb[j], acc[i][j]);
        }
    }

    float w2j[8], b1j[8];
    #pragma unroll
    for (int jj = 0; jj < 8; ++jj) {
        int c = (jj < 4) ? (tx * 4 + jj) : (64 + tx * 4 + (jj - 4));
        w2j[jj] = W2[c];
        b1j[jj] = b1[c];
    }
    float bias2 = b2[0];
    __syncthreads();
    #pragma unroll
    for (int i = 0; i < 4; ++i) {
        float s = 0.0f;
        #pragma unroll
        for (int jj = 0; jj < 8; ++jj)
            s += fmaxf(acc[i][jj] + b1j[jj], 0.0f) * w2j[jj];
        redv[ty * 4 + i][tx] = s;
    }
    __syncthreads();
    if (tid < 64) {
        float s = 0.0f;
        #pragma unroll
        for (int tt = 0; tt < 16; ++tt) s += redv[tid][tt];
        g[row0 + tid] = s + bias2;
    }
}

// ---------------- K4: output ----------------
__global__ void k_out(const int* __restrict__ finalidx,
                      const float* __restrict__ g, float* __restrict__ out) {
    int rr = blockIdx.x * 256 + threadIdx.x;
    if (rr >= BL_) return;
    int b = rr >> 11;
    out[rr] = g[rr] + g[BL_ + (b << 11) + finalidx[rr]];
}

extern "C" void kernel_launch(void* const* d_in, const int* in_sizes, int n_in,
                              void* d_out, int out_size, void* d_ws, size_t ws_size,
                              hipStream_t stream) {
    const float* context = (const float*)d_in[0];
    const float* W1 = (const float*)d_in[1];
    const float* b1 = (const float*)d_in[2];
    const float* W2 = (const float*)d_in[3];
    const float* b2 = (const float*)d_in[4];
    float* out = (float*)d_out;

    char* ws = (char*)d_ws;
    float*  cn  = (float*)(ws);                  // 8 MB
    float*  en  = (float*)(ws + 8388608);        // 8 MB
    ushort* cnb = (ushort*)(ws + 16777216);      // 4 MB
    ushort* enb = (ushort*)(ws + 20971520);      // 4 MB
    float*  g   = (float*)(ws + 25165824);       // 128 KB
    int* finalidx = (int*)(ws + 25296896);       // 64 KB

    k_norm<<<8192, 256, 0, stream>>>(context, cn, en, cnb, enb);
    k_sim<<<512, 512, 0, stream>>>(cnb, enb, cn, en, finalidx);
    k_feval<<<512, 256, 0, stream>>>(cn, W1, b1, W2, b2, g);
    k_out<<<BL_ / 256, 256, 0, stream>>>(finalidx, g, out);
}

// Round 2
// 126.349 us; speedup vs baseline: 1.2758x; 1.2758x over previous
//
#include <hip/hip_runtime.h>
#include <hip/hip_bf16.h>

#define B_ 8
#define L_ 2048
#define D_ 128
#define BL_ (B_ * L_)
#define DELTA2 0.016f   // 2*delta; delta=0.008 >= rigorous bf16 dot bound (0.004) with 2x margin
#define QCAP 4096

typedef __attribute__((ext_vector_type(8))) short bf16x8;
typedef __attribute__((ext_vector_type(4))) float f32x4;

__device__ __forceinline__ void gload_lds16(const void* g, void* l) {
    __builtin_amdgcn_global_load_lds(
        (const __attribute__((address_space(1))) unsigned int*)g,
        (__attribute__((address_space(3))) unsigned int*)l, 16, 0, 0);
}

// ---------------- K1: normalize + bf16 cast ----------------
__global__ void k_norm(const float* __restrict__ ctx,
                       float* __restrict__ cn, float* __restrict__ en,
                       ushort* __restrict__ cnb, ushort* __restrict__ enb) {
    int wid  = blockIdx.x * 4 + (threadIdx.x >> 6);   // 0..32767
    int lane = threadIdx.x & 63;
    int b   = wid >> 12;
    int rem = wid & 4095;
    int c   = rem >> 11;
    int l   = rem & 2047;

    const float* src = ctx + (size_t)wid * D_;
    float2 v = ((const float2*)src)[lane];
    float ss = v.x * v.x + v.y * v.y;
    #pragma unroll
    for (int off = 32; off; off >>= 1) ss += __shfl_down(ss, off, 64);
    ss = __shfl(ss, 0, 64);
    float n = fmaxf(sqrtf(ss), 1e-8f);
    float ox = v.x / n, oy = v.y / n;

    size_t ro = (size_t)(b * L_ + l) * D_;
    float* dst = (c == 0 ? cn : en) + ro;
    ((float2*)dst)[lane] = make_float2(ox, oy);

    __hip_bfloat16 hx = __float2bfloat16(ox), hy = __float2bfloat16(oy);
    ushort ux = *(ushort*)&hx, uy = *(ushort*)&hy;
    ushort* dstb = (c == 0 ? cnb : enb) + ro;
    ((ushort2*)dstb)[lane] = make_ushort2(ux, uy);
}

// ---------------- K2: fused sim + argmax, async-DMA pipelined ----------------
// grid 256: b = blk&7 (XCD-local), rb = blk>>3. Block = 64 rows x 2048 cols, 8 waves.
// Wave w owns cols {sc*256 + w*32 .. +32} for sc=0..7. B sub-chunks (32 cols = 8KB)
// are streamed global->LDS with global_load_lds into a PER-WAVE-PRIVATE double
// buffer (no barriers in the hot loop; counted vmcnt(8) keeps next chunk in flight).
// Two passes: pass 1 = rowmax (register fmax only), pass 2 = recompute + capture
// candidates >= rowmax - 2*delta; phase 3 = exact double dots, 4 candidates/wave.
__global__ __launch_bounds__(512, 2) void k_sim(const ushort* __restrict__ cnb,
                                                const ushort* __restrict__ enb,
                                                const float* __restrict__ cn,
                                                const float* __restrict__ en,
                                                int* __restrict__ finalidx) {
    __shared__ char Bsm[8][2][8192];          // 128 KB: per-wave private double buffer
    __shared__ float wrowmax[8][64];
    __shared__ float rowth_l[64];
    __shared__ unsigned long long best[64];
    __shared__ int qbuf[QCAP];
    __shared__ int qn;

    const int bid = blockIdx.x;
    const int b = bid & 7, rb = bid >> 3;
    const int row0 = rb * 64;
    const int tid = threadIdx.x;
    const int wave = tid >> 6, lane = tid & 63;
    const int m = lane & 15, q = lane >> 4;

    if (tid == 0) qn = 0;
    if (tid < 64) best[tid] = 0ULL;

    const ushort* Ab  = cnb + ((size_t)(b * L_) + row0) * D_;
    const ushort* Bb0 = enb + (size_t)(b * L_) * D_;
    const char* gw = (const char*)Bb0 + (size_t)wave * 8192;   // wave's 32-col slice, chunk 0
    char* l0 = &Bsm[wave][0][0];
    char* l1 = &Bsm[wave][1][0];

    // A fragments: 64 rows x 128 k in registers for the whole kernel (64 VGPRs)
    bf16x8 Areg[16];
    #pragma unroll
    for (int rt = 0; rt < 4; ++rt)
        #pragma unroll
        for (int kc = 0; kc < 4; ++kc)
            Areg[rt * 4 + kc] = *(const bf16x8*)(Ab + (size_t)(rt * 16 + m) * D_ + kc * 32 + q * 8);

    // stage sub-chunk sc (8KB = 8 x 1KB wave-instructions) into lbuf
    auto STAGE = [&](int sc, char* lbuf) {
        const char* src = gw + (size_t)sc * 65536 + (size_t)lane * 16;
        #pragma unroll
        for (int i = 0; i < 8; ++i)
            gload_lds16(src + i * 1024, lbuf + i * 1024);
    };
    // 64 rows x 32 cols x 128 k from LDS fragments
    auto TILE = [&](const char* lbuf, f32x4 acc[4][2]) {
        #pragma unroll
        for (int rt = 0; rt < 4; ++rt)
            #pragma unroll
            for (int ct = 0; ct < 2; ++ct) acc[rt][ct] = (f32x4){0.f, 0.f, 0.f, 0.f};
        #pragma unroll
        for (int kc = 0; kc < 4; ++kc) {
            bf16x8 bf0 = *(const bf16x8*)(lbuf + (size_t)(m) * 256 + kc * 64 + q * 16);
            bf16x8 bf1 = *(const bf16x8*)(lbuf + (size_t)(16 + m) * 256 + kc * 64 + q * 16);
            #pragma unroll
            for (int rt = 0; rt < 4; ++rt) {
                acc[rt][0] = __builtin_amdgcn_mfma_f32_16x16x32_bf16(Areg[rt * 4 + kc], bf0, acc[rt][0], 0, 0, 0);
                acc[rt][1] = __builtin_amdgcn_mfma_f32_16x16x32_bf16(Areg[rt * 4 + kc], bf1, acc[rt][1], 0, 0, 0);
            }
        }
    };

    float runmax[16];
    #pragma unroll
    for (int s = 0; s < 16; ++s) runmax[s] = -3.0e38f;

    // ---------------- PASS 1: rowmax only ----------------
    STAGE(0, l0);
    #pragma unroll 1
    for (int scp = 0; scp < 4; ++scp) {
        int sc0 = scp * 2;
        STAGE(sc0 + 1, l1);
        asm volatile("s_waitcnt vmcnt(8)" ::: "memory");
        {
            f32x4 acc[4][2];
            TILE(l0, acc);
            #pragma unroll
            for (int rt = 0; rt < 4; ++rt)
                #pragma unroll
                for (int reg = 0; reg < 4; ++reg)
                    runmax[rt * 4 + reg] = fmaxf(runmax[rt * 4 + reg],
                                                 fmaxf(acc[rt][0][reg], acc[rt][1][reg]));
        }
        if (scp < 3) {
            STAGE(sc0 + 2, l0);
            asm volatile("s_waitcnt vmcnt(8)" ::: "memory");
        } else {
            asm volatile("s_waitcnt vmcnt(0)" ::: "memory");
        }
        {
            f32x4 acc[4][2];
            TILE(l1, acc);
            #pragma unroll
            for (int rt = 0; rt < 4; ++rt)
                #pragma unroll
                for (int reg = 0; reg < 4; ++reg)
                    runmax[rt * 4 + reg] = fmaxf(runmax[rt * 4 + reg],
                                                 fmaxf(acc[rt][0][reg], acc[rt][1][reg]));
        }
    }

    // cross-lane (m) then cross-wave row-max reduction
    #pragma unroll
    for (int s = 0; s < 16; ++s) {
        float v = runmax[s];
        v = fmaxf(v, __shfl_xor(v, 1, 64));
        v = fmaxf(v, __shfl_xor(v, 2, 64));
        v = fmaxf(v, __shfl_xor(v, 4, 64));
        v = fmaxf(v, __shfl_xor(v, 8, 64));
        runmax[s] = v;
    }
    if (m == 0) {
        #pragma unroll
        for (int rt = 0; rt < 4; ++rt)
            #pragma unroll
            for (int reg = 0; reg < 4; ++reg)
                wrowmax[wave][rt * 16 + q * 4 + reg] = runmax[rt * 4 + reg];
    }
    __syncthreads();
    if (tid < 64) {
        float rm = wrowmax[0][tid];
        #pragma unroll
        for (int w = 1; w < 8; ++w) rm = fmaxf(rm, wrowmax[w][tid]);
        rowth_l[tid] = rm - DELTA2;
    }
    __syncthreads();
    float rowth_r[16];
    #pragma unroll
    for (int rt = 0; rt < 4; ++rt)
        #pragma unroll
        for (int reg = 0; reg < 4; ++reg)
            rowth_r[rt * 4 + reg] = rowth_l[rt * 16 + q * 4 + reg];

    // ---------------- PASS 2: recompute + capture (MFMA bit-identical) ----------------
    STAGE(0, l0);
    #pragma unroll 1
    for (int scp = 0; scp < 4; ++scp) {
        int sc0 = scp * 2;
        STAGE(sc0 + 1, l1);
        asm volatile("s_waitcnt vmcnt(8)" ::: "memory");
        {
            f32x4 acc[4][2];
            TILE(l0, acc);
            int col0 = sc0 * 256 + wave * 32;
            #pragma unroll
            for (int rt = 0; rt < 4; ++rt)
                #pragma unroll
                for (int reg = 0; reg < 4; ++reg) {
                    float th = rowth_r[rt * 4 + reg];
                    if (fmaxf(acc[rt][0][reg], acc[rt][1][reg]) >= th) {
                        int row = rt * 16 + q * 4 + reg;
                        #pragma unroll
                        for (int ct = 0; ct < 2; ++ct)
                            if (acc[rt][ct][reg] >= th) {
                                int pos = atomicAdd(&qn, 1);
                                if (pos < QCAP)
                                    qbuf[pos] = (row << 12) | (col0 + ct * 16 + m);
                            }
                    }
                }
        }
        if (scp < 3) {
            STAGE(sc0 + 2, l0);
            asm volatile("s_waitcnt vmcnt(8)" ::: "memory");
        } else {
            asm volatile("s_waitcnt vmcnt(0)" ::: "memory");
        }
        {
            f32x4 acc[4][2];
            TILE(l1, acc);
            int col0 = (sc0 + 1) * 256 + wave * 32;
            #pragma unroll
            for (int rt = 0; rt < 4; ++rt)
                #pragma unroll
                for (int reg = 0; reg < 4; ++reg) {
                    float th = rowth_r[rt * 4 + reg];
                    if (fmaxf(acc[rt][0][reg], acc[rt][1][reg]) >= th) {
                        int row = rt * 16 + q * 4 + reg;
                        #pragma unroll
                        for (int ct = 0; ct < 2; ++ct)
                            if (acc[rt][ct][reg] >= th) {
                                int pos = atomicAdd(&qn, 1);
                                if (pos < QCAP)
                                    qbuf[pos] = (row << 12) | (col0 + ct * 16 + m);
                            }
                    }
                }
        }
    }
    __syncthreads();

    // ---------------- PASS 3: exact double dots, 4 candidates/wave (16 lanes each) ----------------
    int qtot = min(qn, QCAP);
    for (int e0 = wave * 4; e0 < qtot; e0 += 32) {
        int e = e0 + q;                       // group q handles candidate e0+q
        bool act = (e < qtot);
        int pc = qbuf[act ? e : (qtot - 1)];
        int rl = (pc >> 12) & 63, col = pc & 0xFFF;
        const float* ar = cn + ((size_t)(b * L_) + row0 + rl) * D_;
        const float* br = en + ((size_t)(b * L_) + col) * D_;
        float4 x0 = ((const float4*)ar)[m * 2], x1 = ((const float4*)ar)[m * 2 + 1];
        float4 y0 = ((const float4*)br)[m * 2], y1 = ((const float4*)br)[m * 2 + 1];
        double s = (double)x0.x * y0.x + (double)x0.y * y0.y +
                   (double)x0.z * y0.z + (double)x0.w * y0.w +
                   (double)x1.x * y1.x + (double)x1.y * y1.y +
                   (double)x1.z * y1.z + (double)x1.w * y1.w;
        s += __shfl_xor(s, 1, 64);
        s += __shfl_xor(s, 2, 64);
        s += __shfl_xor(s, 4, 64);
        s += __shfl_xor(s, 8, 64);
        if (act && m == 0) {
            unsigned long long ub = (unsigned long long)__double_as_longlong(s);
            ub = (ub & 0x8000000000000000ULL) ? ~ub : (ub | 0x8000000000000000ULL);
            ub = (ub & ~0x7FFULL) | (unsigned long long)(2047 - col);  // tie -> lowest col
            atomicMax(&best[rl], ub);
        }
    }
    __syncthreads();
    if (tid < 64)
        finalidx[b * L_ + row0 + tid] = 2047 - (int)(best[tid] & 0x7FFULL);
}

// ---------------- K3: g[r] = relu(X[r]@W1+b1)@W2 + b2, fp32, BM=64 4x8, grid 512 ----------------
__global__ __launch_bounds__(256) void k_feval(
        const float* __restrict__ X,
        const float* __restrict__ W1, const float* __restrict__ b1,
        const float* __restrict__ W2, const float* __restrict__ b2,
        float* __restrict__ g) {
    __shared__ __align__(16) float As[32][68];
    __shared__ __align__(16) float Bs[32][132];
    __shared__ float redv[64][16];

    int tid = threadIdx.x;
    int tx = tid & 15, ty = tid >> 4;
    int r  = tid >> 3, kg = tid & 7;
    int row0 = blockIdx.x * 64;
    const float* Ab = X + (size_t)row0 * D_;

    float acc[4][8];
    #pragma unroll
    for (int i = 0; i < 4; ++i)
        #pragma unroll
        for (int j = 0; j < 8; ++j) acc[i][j] = 0.0f;

    for (int kc = 0; kc < 4; ++kc) {
        __syncthreads();
        #pragma unroll
        for (int p = 0; p < 2; ++p) {
            int rr = r + 32 * p;
            float4 v = *(const float4*)(Ab + (size_t)rr * D_ + kc * 32 + kg * 4);
            As[kg][rr]      = v.x;
            As[8 + kg][rr]  = v.y;
            As[16 + kg][rr] = v.z;
            As[24 + kg][rr] = v.w;
        }
        {
            int kr = r, phys = (kr & 3) * 8 + (kr >> 2);
            const float* srcp = W1 + (size_t)(kc * 32 + kr) * D_ + kg * 16;
            #pragma unroll
            for (int qq = 0; qq < 4; ++qq)
                *(float4*)&Bs[phys][kg * 16 + qq * 4] = *(const float4*)(srcp + qq * 4);
        }
        __syncthreads();
        #pragma unroll
        for (int k = 0; k < 32; ++k) {
            float a[4], bb[8];
            *(float4*)&a[0]  = *(const float4*)&As[k][ty * 4];
            *(float4*)&bb[0] = *(const float4*)&Bs[k][tx * 4];
            *(float4*)&bb[4] = *(const float4*)&Bs[k][64 + tx * 4];
            #pragma unroll
            for (int i = 0; i < 4; ++i)
                #pragma unroll
                for (int j = 0; j < 8; ++j)
                    acc[i][j] = fmaf(a[i], bb[j], acc[i][j]);
        }
    }

    float w2j[8], b1j[8];
    #pragma unroll
    for (int jj = 0; jj < 8; ++jj) {
        int c = (jj < 4) ? (tx * 4 + jj) : (64 + tx * 4 + (jj - 4));
        w2j[jj] = W2[c];
        b1j[jj] = b1[c];
    }
    float bias2 = b2[0];
    __syncthreads();
    #pragma unroll
    for (int i = 0; i < 4; ++i) {
        float s = 0.0f;
        #pragma unroll
        for (int jj = 0; jj < 8; ++jj)
            s += fmaxf(acc[i][jj] + b1j[jj], 0.0f) * w2j[jj];
        redv[ty * 4 + i][tx] = s;
    }
    __syncthreads();
    if (tid < 64) {
        float s = 0.0f;
        #pragma unroll
        for (int tt = 0; tt < 16; ++tt) s += redv[tid][tt];
        g[row0 + tid] = s + bias2;
    }
}

// ---------------- K4: output ----------------
__global__ void k_out(const int* __restrict__ finalidx,
                      const float* __restrict__ g, float* __restrict__ out) {
    int rr = blockIdx.x * 256 + threadIdx.x;
    if (rr >= BL_) return;
    int b = rr >> 11;
    out[rr] = g[rr] + g[BL_ + (b << 11) + finalidx[rr]];
}

extern "C" void kernel_launch(void* const* d_in, const int* in_sizes, int n_in,
                              void* d_out, int out_size, void* d_ws, size_t ws_size,
                              hipStream_t stream) {
    const float* context = (const float*)d_in[0];
    const float* W1 = (const float*)d_in[1];
    const float* b1 = (const float*)d_in[2];
    const float* W2 = (const float*)d_in[3];
    const float* b2 = (const float*)d_in[4];
    float* out = (float*)d_out;

    char* ws = (char*)d_ws;
    float*  cn  = (float*)(ws);                  // 8 MB
    float*  en  = (float*)(ws + 8388608);        // 8 MB
    ushort* cnb = (ushort*)(ws + 16777216);      // 4 MB
    ushort* enb = (ushort*)(ws + 20971520);      // 4 MB
    float*  g   = (float*)(ws + 25165824);       // 128 KB
    int* finalidx = (int*)(ws + 25296896);       // 64 KB

    k_norm<<<8192, 256, 0, stream>>>(context, cn, en, cnb, enb);
    k_sim<<<256, 512, 0, stream>>>(cnb, enb, cn, en, finalidx);
    k_feval<<<512, 256, 0, stream>>>(cn, W1, b1, W2, b2, g);
    k_out<<<BL_ / 256, 256, 0, stream>>>(finalidx, g, out);
}